// Round 7
// baseline (225.372 us; speedup 1.0000x reference)
//
#include <hip/hip_runtime.h>

#define N_NODES 32768
#define N_EDGES 16384
#define DEG 4
#define KPE 8
#define DIM 128
#define EDIM 64
#define MAXC 64   // max containing-(node,slot) entries per edge; Poisson(8) -> P(>64) ~ 1e-40

typedef float f32x4 __attribute__((ext_vector_type(4)));
typedef __bf16 bf16x8 __attribute__((ext_vector_type(8)));
typedef __bf16 bf16x2 __attribute__((ext_vector_type(2)));
typedef unsigned short u16x8 __attribute__((ext_vector_type(8)));
typedef unsigned int u32;
typedef unsigned int u32x4 __attribute__((ext_vector_type(4)));
typedef int i32x4 __attribute__((ext_vector_type(4)));

static __device__ __forceinline__ unsigned short f2bf(float f) {
  union { float f; unsigned int u; } v; v.f = f;
  unsigned int r = (v.u + 0x7FFFu + ((v.u >> 16) & 1u)) >> 16;
  return (unsigned short)r;
}
static __device__ __forceinline__ float bflo(unsigned int v) {
  union { unsigned int u; float f; } x; x.u = v << 16; return x.f;
}
static __device__ __forceinline__ float bfhi(unsigned int v) {
  union { unsigned int u; float f; } x; x.u = v & 0xffff0000u; return x.f;
}
static __device__ __forceinline__ float f16tof(unsigned short h) {
  return (float)__builtin_bit_cast(_Float16, h);
}
static __device__ __forceinline__ unsigned short ftof16(float f) {
  return __builtin_bit_cast(unsigned short, (_Float16)f);
}

#if __has_builtin(__builtin_amdgcn_fdot2_f32_bf16)
static __device__ __forceinline__ float dot2bf(unsigned int a, unsigned int b, float c) {
  return __builtin_amdgcn_fdot2_f32_bf16(
      __builtin_bit_cast(bf16x2, a), __builtin_bit_cast(bf16x2, b), c, false);
}
#else
static __device__ __forceinline__ float dot2bf(unsigned int a, unsigned int b, float c) {
  c = fmaf(bflo(a), bflo(b), c);
  return fmaf(bfhi(a), bfhi(b), c);
}
#endif

// packed f16x2 global atomic add (global_atomic_pk_add_f16 on CDNA); CAS fallback.
static __device__ __forceinline__ void atomAddF16x2(unsigned short* p, u32 val) {
#if __has_builtin(__builtin_amdgcn_global_atomic_fadd_v2f16)
  typedef _Float16 hf2 __attribute__((ext_vector_type(2)));
  __builtin_amdgcn_global_atomic_fadd_v2f16(
      (__attribute__((address_space(1))) hf2*)p, __builtin_bit_cast(hf2, val));
#else
  u32* q = (u32*)p;
  u32 old = *q, assumed;
  do {
    assumed = old;
    _Float16 lo = __builtin_bit_cast(_Float16, (unsigned short)(assumed & 0xffff)) +
                  __builtin_bit_cast(_Float16, (unsigned short)(val & 0xffff));
    _Float16 hi = __builtin_bit_cast(_Float16, (unsigned short)(assumed >> 16)) +
                  __builtin_bit_cast(_Float16, (unsigned short)(val >> 16));
    u32 nv = (u32)__builtin_bit_cast(unsigned short, lo) |
             ((u32)__builtin_bit_cast(unsigned short, hi) << 16);
    old = atomicCAS(q, assumed, nv);
  } while (old != assumed);
#endif
}

// ---------------- zero cnt + ctx (poison!) before wprep/ectx ------------------
__global__ __launch_bounds__(256) void zcnt_kernel(int* __restrict__ cnt,
                                                   unsigned short* __restrict__ ctx)
{
  int id = blockIdx.x * 256 + threadIdx.x;
  if (id < N_EDGES / 4) {
    i32x4 z = {0, 0, 0, 0};
    ((i32x4*)cnt)[id] = z;
  }
  if (id < (N_NODES * DIM) / 8) {              // 524288 uint4 of fp16 zeros
    u32x4 z = {0, 0, 0, 0};
    ((u32x4*)ctx)[id] = z;
  }
}

// ---------------- weight combine + reverse-CSR build --------------------------
// CW=[0.25*Wq@Wlin; Wk@Wlin; Wv@Wlin], CWE=Wk@Wedge, Wob=bf16(Wo).
// rev[e][0..cnt[e]) = packed (n*4+d) for every (n,d) with node_edges[n][d]==e.
// Slot order is atomic-nondeterministic but each entry owns its own (n,d)
// output downstream, so results are order-independent.
__global__ __launch_bounds__(256) void wprep_kernel(
    const float* __restrict__ Wq, const float* __restrict__ Wk,
    const float* __restrict__ Wv, const float* __restrict__ Wlin,
    const float* __restrict__ Wedge, const float* __restrict__ Wo,
    const int* __restrict__ node_edges,
    unsigned short* __restrict__ CW, unsigned short* __restrict__ CWE,
    unsigned short* __restrict__ Wob, int* __restrict__ cnt, int* __restrict__ rev)
{
  int id = blockIdx.x * 256 + threadIdx.x;
  if (id < 384 * 128) {
    int j = id >> 7, i = id & 127;
    const float* wrow; float scale = 1.0f;
    if (j < 128)      { wrow = Wq + j * 128; scale = 0.25f; }
    else if (j < 256) { wrow = Wk + (j - 128) * 128; }
    else              { wrow = Wv + (j - 256) * 128; }
    float s = 0.f;
    #pragma unroll 8
    for (int m = 0; m < 128; ++m) s += wrow[m] * Wlin[m * 128 + i];
    CW[id] = f2bf(s * scale);
  } else if (id < 384 * 128 + 128 * 64) {
    int id2 = id - 384 * 128; int j = id2 >> 6, t = id2 & 63;
    float s = 0.f;
    #pragma unroll 8
    for (int m = 0; m < 128; ++m) s += Wk[j * 128 + m] * Wedge[m * 64 + t];
    CWE[id2] = f2bf(s);
  } else if (id < 384 * 128 + 128 * 64 + 128 * 128) {
    int id3 = id - (384 * 128 + 128 * 64);
    Wob[id3] = f2bf(Wo[id3]);
  } else {
    int t = id - (384 * 128 + 128 * 64 + 128 * 128);   // t = n*DEG + d
    if (t < N_NODES * DEG) {
      int e = node_edges[t];
      int pos = atomicAdd(&cnt[e], 1);
      if (pos < MAXC) rev[(size_t)e * MAXC + pos] = t;
    }
  }
}

// ---------------- G12: fused g1 + g2 ------------------------------------------
// Operand-swapped MFMA (acc = mfma(bu, av)) computes D^T: each lane's 4 acc
// regs are 4 CONSECUTIVE OUTPUT COLUMNS of one row -> one 8 B store replaces
// four scattered 2 B stores. Bias becomes a per-lane float4 load. Bit-identical.
__global__ __launch_bounds__(256) void g12_kernel(
    const float* __restrict__ x, const unsigned short* __restrict__ CW,
    const float* __restrict__ bq, const float* __restrict__ bv,
    unsigned short* __restrict__ qb, unsigned short* __restrict__ Kb,
    unsigned short* __restrict__ Vb,
    const float* __restrict__ ea, const unsigned short* __restrict__ CWE,
    const float* __restrict__ bk, unsigned short* __restrict__ WeKb)
{
  const int wave = threadIdx.x >> 6, lane = threadIdx.x & 63;
  const int r16 = lane & 15, quad = lane >> 4;

  if (blockIdx.x < 512) {
    const int m0 = blockIdx.x * 64 + wave * 16;
    u16x8 av[4];
    const float* arow = x + (size_t)(m0 + r16) * DIM + quad * 8;
    #pragma unroll
    for (int kk = 0; kk < 4; ++kk) {
      float4 a0 = *(const float4*)(arow + kk * 32);
      float4 a1 = *(const float4*)(arow + kk * 32 + 4);
      u16x8 au;
      au[0] = f2bf(a0.x); au[1] = f2bf(a0.y); au[2] = f2bf(a0.z); au[3] = f2bf(a0.w);
      au[4] = f2bf(a1.x); au[5] = f2bf(a1.y); au[6] = f2bf(a1.z); au[7] = f2bf(a1.w);
      av[kk] = au;
    }
    #pragma unroll
    for (int g = 0; g < 6; ++g) {
      f32x4 acc[4];
      const f32x4 z = {0.f, 0.f, 0.f, 0.f};
      acc[0] = z; acc[1] = z; acc[2] = z; acc[3] = z;
      #pragma unroll
      for (int kk = 0; kk < 4; ++kk) {
        #pragma unroll
        for (int s = 0; s < 4; ++s) {
          u16x8 bu = *(const u16x8*)(CW + (size_t)(g * 64 + s * 16 + r16) * DIM + kk * 32 + quad * 8);
          acc[s] = __builtin_amdgcn_mfma_f32_16x16x32_bf16(
              __builtin_bit_cast(bf16x8, bu), __builtin_bit_cast(bf16x8, av[kk]), acc[s], 0, 0, 0);
        }
      }
      const int arr = g >> 1;               // 0:q 1:K 2:V
      const int colbase = (g & 1) * 64;
      unsigned short* dst = arr == 0 ? qb : (arr == 1 ? Kb : Vb);
      const int m = m0 + r16;
      #pragma unroll
      for (int s = 0; s < 4; ++s) {
        const int j0 = colbase + s * 16 + quad * 4;
        float4 b4 = {0.f, 0.f, 0.f, 0.f};
        if (arr == 0) {
          float4 t = *(const float4*)(bq + j0);
          b4.x = 0.25f * t.x; b4.y = 0.25f * t.y; b4.z = 0.25f * t.z; b4.w = 0.25f * t.w;
        } else if (arr == 2) {
          b4 = *(const float4*)(bv + j0);
        }
        u32 lo = (u32)f2bf(acc[s][0] + b4.x) | ((u32)f2bf(acc[s][1] + b4.y) << 16);
        u32 hi = (u32)f2bf(acc[s][2] + b4.z) | ((u32)f2bf(acc[s][3] + b4.w) << 16);
        uint2 st = {lo, hi};
        *(uint2*)(dst + (size_t)m * DIM + j0) = st;
      }
    }
  } else {
    const int idx = blockIdx.x - 512;
    const int m0 = (idx >> 1) * 64 + wave * 16;
    const int n0 = (idx & 1) * 64;
    f32x4 acc[4];
    const f32x4 z = {0.f, 0.f, 0.f, 0.f};
    acc[0] = z; acc[1] = z; acc[2] = z; acc[3] = z;
    const float* arow = ea + (size_t)(m0 + r16) * EDIM + quad * 8;
    #pragma unroll
    for (int kk = 0; kk < 2; ++kk) {
      float4 a0 = *(const float4*)(arow + kk * 32);
      float4 a1 = *(const float4*)(arow + kk * 32 + 4);
      u16x8 au;
      au[0] = f2bf(a0.x); au[1] = f2bf(a0.y); au[2] = f2bf(a0.z); au[3] = f2bf(a0.w);
      au[4] = f2bf(a1.x); au[5] = f2bf(a1.y); au[6] = f2bf(a1.z); au[7] = f2bf(a1.w);
      bf16x8 av = __builtin_bit_cast(bf16x8, au);
      #pragma unroll
      for (int s = 0; s < 4; ++s) {
        u16x8 bu = *(const u16x8*)(CWE + (size_t)(n0 + s * 16 + r16) * EDIM + kk * 32 + quad * 8);
        acc[s] = __builtin_amdgcn_mfma_f32_16x16x32_bf16(
            __builtin_bit_cast(bf16x8, bu), av, acc[s], 0, 0, 0);
      }
    }
    const int m = m0 + r16;
    #pragma unroll
    for (int s = 0; s < 4; ++s) {
      const int j0 = n0 + s * 16 + quad * 4;
      float4 b4 = *(const float4*)(bk + j0);
      u32 lo = (u32)f2bf(acc[s][0] + b4.x) | ((u32)f2bf(acc[s][1] + b4.y) << 16);
      u32 hi = (u32)f2bf(acc[s][2] + b4.z) | ((u32)f2bf(acc[s][3] + b4.w) << 16);
      uint2 st = {lo, hi};
      *(uint2*)(WeKb + (size_t)m * DIM + j0) = st;
    }
  }
}

// ---------------- ESCORE: per-edge score kernel -------------------------------
// 1 wave = 1 edge. Lane = (member g = lane>>3, head j = lane&7). Each lane's
// 16-dim chunk IS head j -> a lane's local dot is a complete head score; no
// cross-lane reduction. 1-ahead q prefetch (r5 structure, low VGPR).
__global__ __launch_bounds__(256) void escore_kernel(
    const unsigned short* __restrict__ qb, const unsigned short* __restrict__ Kb,
    const unsigned short* __restrict__ WeKb, const int* __restrict__ enodes,
    const int* __restrict__ cnt, const int* __restrict__ rev,
    unsigned short* __restrict__ S)
{
  const int wave = threadIdx.x >> 6, lane = threadIdx.x & 63;
  const int e = blockIdx.x * 4 + wave;
  const int g = lane >> 3, j = lane & 7;

  int c_n = cnt[e]; if (c_n > MAXC) c_n = MAXC;
  if (c_n == 0) return;
  int rv = rev[(size_t)e * MAXC + lane];

  int mid = enodes[(size_t)e * KPE + g];
  u32x4 k0 = *(const u32x4*)(Kb + (size_t)mid * DIM + j * 16);
  u32x4 k1 = *(const u32x4*)(Kb + (size_t)mid * DIM + j * 16 + 8);
  u32x4 w0 = *(const u32x4*)(WeKb + (size_t)e * DIM + j * 16);
  u32x4 w1 = *(const u32x4*)(WeKb + (size_t)e * DIM + j * 16 + 8);

  int pk = __shfl(rv, 0);
  u32x4 qa0 = *(const u32x4*)(qb + (size_t)(pk >> 2) * DIM + j * 16);
  u32x4 qa1 = *(const u32x4*)(qb + (size_t)(pk >> 2) * DIM + j * 16 + 8);

  for (int c = 0; c < c_n; ++c) {
    const int n = pk >> 2, d = pk & 3;
    u32x4 q0 = qa0, q1 = qa1;
    if (c + 1 < c_n) {
      pk = __shfl(rv, c + 1);
      qa0 = *(const u32x4*)(qb + (size_t)(pk >> 2) * DIM + j * 16);
      qa1 = *(const u32x4*)(qb + (size_t)(pk >> 2) * DIM + j * 16 + 8);
    }
    float s = 0.f;
    s = dot2bf(q0.x, k0.x, s); s = dot2bf(q0.y, k0.y, s);
    s = dot2bf(q0.z, k0.z, s); s = dot2bf(q0.w, k0.w, s);
    s = dot2bf(q1.x, k1.x, s); s = dot2bf(q1.y, k1.y, s);
    s = dot2bf(q1.z, k1.z, s); s = dot2bf(q1.w, k1.w, s);
    s = dot2bf(q0.x, w0.x, s); s = dot2bf(q0.y, w0.y, s);
    s = dot2bf(q0.z, w0.z, s); s = dot2bf(q0.w, w0.w, s);
    s = dot2bf(q1.x, w1.x, s); s = dot2bf(q1.y, w1.y, s);
    s = dot2bf(q1.z, w1.z, s); s = dot2bf(q1.w, w1.w, s);
    // S[n][key=d*8+g][head=j]: flat ushort idx = n*256 + d*64 + g*8 + j
    S[(size_t)n * 256 + d * 64 + g * 8 + j] = ftof16(s);
  }
}

// ---------------- NSM: per-node softmax, S[n][l][h] -> P[n][h][l] in place ----
__global__ __launch_bounds__(256) void nsm_kernel(unsigned short* __restrict__ SP)
{
  const int wave = threadIdx.x >> 6, lane = threadIdx.x & 63;
  const int n = blockIdx.x * 4 + wave;
  const int l = lane & 31, hp = lane >> 5;
  unsigned short* row = SP + (size_t)n * 256;

  uint2 sv = *(const uint2*)(row + l * 8 + hp * 4);
  float s4[4] = { f16tof(sv.x & 0xffff), f16tof(sv.x >> 16),
                  f16tof(sv.y & 0xffff), f16tof(sv.y >> 16) };
  unsigned short pr[4];
  #pragma unroll
  for (int hi = 0; hi < 4; ++hi) {
    float vmax = s4[hi];
    #pragma unroll
    for (int off = 16; off >= 1; off >>= 1)
      vmax = fmaxf(vmax, __shfl_xor(vmax, off, 32));
    float ex = __expf(s4[hi] - vmax);
    float sum = ex;
    #pragma unroll
    for (int off = 16; off >= 1; off >>= 1)
      sum += __shfl_xor(sum, off, 32);
    pr[hi] = ftof16(ex / sum);
  }
  #pragma unroll
  for (int hi = 0; hi < 4; ++hi)
    row[(hp * 4 + hi) * 32 + l] = pr[hi];
}

// ---------------- ECTX: per-edge context, ATOMIC f16x2 accumulate -------------
// 1 wave = 1 edge. Lane = dim pair (c0 = lane*2, head h = lane>>3).
// r11: instead of writing 33.5 MB of per-(n,d) partials for g4 to re-read and
// sum, accumulate directly into ctx[n][dim] (fp16, zeroed in zcnt) via
// global_atomic_pk_add_f16. Exactly DEG=4 adds per cell, no return value ->
// fire-and-forget; saves ~50 MB of stream traffic.
__global__ __launch_bounds__(256) void ectx_kernel(
    const unsigned short* __restrict__ Vb, const unsigned short* __restrict__ P,
    const int* __restrict__ enodes, const int* __restrict__ cnt,
    const int* __restrict__ rev, unsigned short* __restrict__ ctx)
{
  const int wave = threadIdx.x >> 6, lane = threadIdx.x & 63;
  const int e = blockIdx.x * 4 + wave;
  const int c0 = lane * 2, h = lane >> 3;

  int c_n = cnt[e]; if (c_n > MAXC) c_n = MAXC;
  if (c_n == 0) return;
  int rv = rev[(size_t)e * MAXC + lane];

  const int* ep = enodes + (size_t)e * KPE;
  i32x4 a4 = *(const i32x4*)ep;
  i32x4 b4 = *(const i32x4*)(ep + 4);
  int id[8] = {a4.x, a4.y, a4.z, a4.w, b4.x, b4.y, b4.z, b4.w};
  u32 vv[8];
  #pragma unroll
  for (int k = 0; k < 8; ++k) vv[k] = *(const u32*)(Vb + (size_t)id[k] * DIM + c0);

  int pk = __shfl(rv, 0);
  uint4 pva = *(const uint4*)(P + (size_t)(pk >> 2) * 256 + h * 32 + (pk & 3) * 8);

  for (int c = 0; c < c_n; ++c) {
    const int n = pk >> 2;
    uint4 pv = pva;
    if (c + 1 < c_n) {
      pk = __shfl(rv, c + 1);
      pva = *(const uint4*)(P + (size_t)(pk >> 2) * 256 + h * 32 + (pk & 3) * 8);
    }
    float p0 = f16tof(pv.x & 0xffff), p1 = f16tof(pv.x >> 16);
    float p2 = f16tof(pv.y & 0xffff), p3 = f16tof(pv.y >> 16);
    float p4 = f16tof(pv.z & 0xffff), p5 = f16tof(pv.z >> 16);
    float p6 = f16tof(pv.w & 0xffff), p7 = f16tof(pv.w >> 16);
    float a0 = 0.f, a1 = 0.f;
    a0 = fmaf(p0, bflo(vv[0]), a0); a1 = fmaf(p0, bfhi(vv[0]), a1);
    a0 = fmaf(p1, bflo(vv[1]), a0); a1 = fmaf(p1, bfhi(vv[1]), a1);
    a0 = fmaf(p2, bflo(vv[2]), a0); a1 = fmaf(p2, bfhi(vv[2]), a1);
    a0 = fmaf(p3, bflo(vv[3]), a0); a1 = fmaf(p3, bfhi(vv[3]), a1);
    a0 = fmaf(p4, bflo(vv[4]), a0); a1 = fmaf(p4, bfhi(vv[4]), a1);
    a0 = fmaf(p5, bflo(vv[5]), a0); a1 = fmaf(p5, bfhi(vv[5]), a1);
    a0 = fmaf(p6, bflo(vv[6]), a0); a1 = fmaf(p6, bfhi(vv[6]), a1);
    a0 = fmaf(p7, bflo(vv[7]), a0); a1 = fmaf(p7, bfhi(vv[7]), a1);
    u32 pk2 = (u32)ftof16(a0) | ((u32)ftof16(a1) << 16);
    atomAddF16x2(ctx + (size_t)n * DIM + c0, pk2);
  }
}

// ---------------- G4: ctx[N,128](fp16) @ Wo^T + bo, ReLU ----------------------
// Operand-swapped MFMA -> lane owns 4 consecutive out columns = float4 store.
__global__ __launch_bounds__(256) void g4_kernel(
    const unsigned short* __restrict__ ctx, const unsigned short* __restrict__ Wob,
    const float* __restrict__ bo, float* __restrict__ out)
{
  const int wave = threadIdx.x >> 6, lane = threadIdx.x & 63;
  const int r16 = lane & 15, quad = lane >> 4;
  const int m0 = blockIdx.x * 64 + wave * 16;

  f32x4 acc[2][4];
  const f32x4 z = {0.f, 0.f, 0.f, 0.f};
  #pragma unroll
  for (int hf = 0; hf < 2; ++hf) { acc[hf][0] = z; acc[hf][1] = z; acc[hf][2] = z; acc[hf][3] = z; }

  #pragma unroll
  for (int kk = 0; kk < 4; ++kk) {
    u16x8 t = *(const u16x8*)(ctx + (size_t)(m0 + r16) * DIM + kk * 32 + quad * 8);
    u16x8 au;
    #pragma unroll
    for (int i = 0; i < 8; ++i) au[i] = f2bf(f16tof(t[i]));
    bf16x8 av = __builtin_bit_cast(bf16x8, au);
    #pragma unroll
    for (int hf = 0; hf < 2; ++hf) {
      #pragma unroll
      for (int s = 0; s < 4; ++s) {
        u16x8 bu = *(const u16x8*)(Wob + (size_t)(hf * 64 + s * 16 + r16) * DIM + kk * 32 + quad * 8);
        acc[hf][s] = __builtin_amdgcn_mfma_f32_16x16x32_bf16(
            __builtin_bit_cast(bf16x8, bu), av, acc[hf][s], 0, 0, 0);
      }
    }
  }

  const int m = m0 + r16;
  #pragma unroll
  for (int hf = 0; hf < 2; ++hf) {
    #pragma unroll
    for (int s = 0; s < 4; ++s) {
      const int j0 = hf * 64 + s * 16 + quad * 4;
      float4 b4 = *(const float4*)(bo + j0);
      float4 v;
      v.x = acc[hf][s][0] + b4.x; v.x = v.x > 0.f ? v.x : 0.f;
      v.y = acc[hf][s][1] + b4.y; v.y = v.y > 0.f ? v.y : 0.f;
      v.z = acc[hf][s][2] + b4.z; v.z = v.z > 0.f ? v.z : 0.f;
      v.w = acc[hf][s][3] + b4.w; v.w = v.w > 0.f ? v.w : 0.f;
      *(float4*)(out + (size_t)m * DIM + j0) = v;
    }
  }
}

extern "C" void kernel_launch(void* const* d_in, const int* in_sizes, int n_in,
                              void* d_out, int out_size, void* d_ws, size_t ws_size,
                              hipStream_t stream)
{
  const float* x     = (const float*)d_in[0];
  const float* ea    = (const float*)d_in[1];
  const int* nedges  = (const int*)d_in[2];
  const int* enodes  = (const int*)d_in[3];
  const float* Wlin  = (const float*)d_in[4];
  const float* Wedge = (const float*)d_in[5];
  const float* Wq    = (const float*)d_in[6];
  const float* Wk    = (const float*)d_in[7];
  const float* Wv    = (const float*)d_in[8];
  const float* bq    = (const float*)d_in[9];
  const float* bk    = (const float*)d_in[10];
  const float* bv    = (const float*)d_in[11];
  const float* Wo    = (const float*)d_in[12];
  const float* bo    = (const float*)d_in[13];
  float* out = (float*)d_out;

  unsigned short* wsp = (unsigned short*)d_ws;
  unsigned short* CW   = wsp;  wsp += 384 * 128;
  unsigned short* CWE  = wsp;  wsp += 128 * 64;
  unsigned short* Wob  = wsp;  wsp += 128 * 128;
  unsigned short* qb   = wsp;  wsp += (size_t)N_NODES * DIM;
  unsigned short* Kb   = wsp;  wsp += (size_t)N_NODES * DIM;
  unsigned short* Vb   = wsp;  wsp += (size_t)N_NODES * DIM;
  unsigned short* WeKb = wsp;  wsp += (size_t)N_EDGES * DIM;
  unsigned short* SP   = wsp;  wsp += (size_t)N_NODES * 256;   // fp16 S -> P in place (16 MB)
  unsigned short* ctx  = wsp;  wsp += (size_t)N_NODES * DIM;   // fp16 atomic accumulator (8.4 MB)
  int* cnt = (int*)wsp;        wsp += N_EDGES * 2;
  int* rev = (int*)wsp;        wsp += (size_t)N_EDGES * MAXC * 2;

  zcnt_kernel<<<dim3(2048), dim3(256), 0, stream>>>(cnt, ctx);
  wprep_kernel<<<dim3(800), dim3(256), 0, stream>>>(
      Wq, Wk, Wv, Wlin, Wedge, Wo, nedges, CW, CWE, Wob, cnt, rev);
  g12_kernel<<<dim3(1024), dim3(256), 0, stream>>>(x, CW, bq, bv, qb, Kb, Vb, ea, CWE, bk, WeKb);
  escore_kernel<<<dim3(N_EDGES / 4), dim3(256), 0, stream>>>(qb, Kb, WeKb, enodes, cnt, rev, SP);
  nsm_kernel<<<dim3(N_NODES / 4), dim3(256), 0, stream>>>(SP);
  ectx_kernel<<<dim3(N_EDGES / 4), dim3(256), 0, stream>>>(Vb, SP, enodes, cnt, rev, ctx);
  g4_kernel<<<dim3(512), dim3(256), 0, stream>>>(ctx, Wob, bo, out);
}

// Round 8
// 205.358 us; speedup vs baseline: 1.0975x; 1.0975x over previous
//
#include <hip/hip_runtime.h>

#define N_NODES 32768
#define N_EDGES 16384
#define DEG 4
#define KPE 8
#define DIM 128
#define EDIM 64

typedef float f32x4 __attribute__((ext_vector_type(4)));
typedef __bf16 bf16x8 __attribute__((ext_vector_type(8)));
typedef __bf16 bf16x2 __attribute__((ext_vector_type(2)));
typedef unsigned short u16x8 __attribute__((ext_vector_type(8)));
typedef unsigned int u32;
typedef unsigned int u32x4 __attribute__((ext_vector_type(4)));
typedef int i32x4 __attribute__((ext_vector_type(4)));

static __device__ __forceinline__ unsigned short f2bf(float f) {
  union { float f; unsigned int u; } v; v.f = f;
  unsigned int r = (v.u + 0x7FFFu + ((v.u >> 16) & 1u)) >> 16;
  return (unsigned short)r;
}
static __device__ __forceinline__ float bflo(unsigned int v) {
  union { unsigned int u; float f; } x; x.u = v << 16; return x.f;
}
static __device__ __forceinline__ float bfhi(unsigned int v) {
  union { unsigned int u; float f; } x; x.u = v & 0xffff0000u; return x.f;
}

#if __has_builtin(__builtin_amdgcn_fdot2_f32_bf16)
static __device__ __forceinline__ float dot2bf(unsigned int a, unsigned int b, float c) {
  return __builtin_amdgcn_fdot2_f32_bf16(
      __builtin_bit_cast(bf16x2, a), __builtin_bit_cast(bf16x2, b), c, false);
}
#else
static __device__ __forceinline__ float dot2bf(unsigned int a, unsigned int b, float c) {
  c = fmaf(bflo(a), bflo(b), c);
  return fmaf(bfhi(a), bfhi(b), c);
}
#endif

// ---------------- weight combine + uidx flatten (r2 structure) ----------------
// CW=[0.25*Wq@Wlin; Wk@Wlin; Wv@Wlin] (384x128), CWE=Wk@Wedge (128x64),
// Wob=bf16(Wo), uidx[n][32] = enodes[node_edges[n][d]][k] (flattened index
// chain: removes one dependent L3 round trip from every attn wave).
__global__ __launch_bounds__(256) void wprep_kernel(
    const float* __restrict__ Wq, const float* __restrict__ Wk,
    const float* __restrict__ Wv, const float* __restrict__ Wlin,
    const float* __restrict__ Wedge, const float* __restrict__ Wo,
    const int* __restrict__ node_edges, const int* __restrict__ enodes,
    unsigned short* __restrict__ CW, unsigned short* __restrict__ CWE,
    unsigned short* __restrict__ Wob, int* __restrict__ uidx)
{
  int id = blockIdx.x * 256 + threadIdx.x;
  if (id < 384 * 128) {
    int j = id >> 7, i = id & 127;
    const float* wrow; float scale = 1.0f;
    if (j < 128)      { wrow = Wq + j * 128; scale = 0.25f; }
    else if (j < 256) { wrow = Wk + (j - 128) * 128; }
    else              { wrow = Wv + (j - 256) * 128; }
    float s = 0.f;
    #pragma unroll 8
    for (int m = 0; m < 128; ++m) s += wrow[m] * Wlin[m * 128 + i];
    CW[id] = f2bf(s * scale);
  } else if (id < 384 * 128 + 128 * 64) {
    int id2 = id - 384 * 128; int j = id2 >> 6, t = id2 & 63;
    float s = 0.f;
    #pragma unroll 8
    for (int m = 0; m < 128; ++m) s += Wk[j * 128 + m] * Wedge[m * 64 + t];
    CWE[id2] = f2bf(s);
  } else if (id < 384 * 128 + 128 * 64 + 128 * 128) {
    int id3 = id - (384 * 128 + 128 * 64);
    Wob[id3] = f2bf(Wo[id3]);
  } else {
    // uidx flatten: t = n*DEG + d in [0, 131072); blocks 288..799 land here.
    int t = id - (384 * 128 + 128 * 64 + 128 * 128);
    int e = node_edges[t];
    i32x4 a = *(const i32x4*)(enodes + (size_t)e * KPE);
    i32x4 b = *(const i32x4*)(enodes + (size_t)e * KPE + 4);
    *(i32x4*)(uidx + (size_t)t * KPE)     = a;
    *(i32x4*)(uidx + (size_t)t * KPE + 4) = b;
  }
}

// ---------------- G12: fused g1 + g2 ------------------------------------------
// Operand-swapped MFMA (acc = mfma(bu, av)) computes D^T: each lane's 4 acc
// regs are 4 CONSECUTIVE OUTPUT COLUMNS of one row -> one 8 B store replaces
// four scattered 2 B stores (validated bit-identical in r6/r7). Bias becomes
// a per-lane float4 load.
__global__ __launch_bounds__(256) void g12_kernel(
    const float* __restrict__ x, const unsigned short* __restrict__ CW,
    const float* __restrict__ bq, const float* __restrict__ bv,
    unsigned short* __restrict__ qb, unsigned short* __restrict__ Kb,
    unsigned short* __restrict__ Vb,
    const float* __restrict__ ea, const unsigned short* __restrict__ CWE,
    const float* __restrict__ bk, unsigned short* __restrict__ WeKb)
{
  const int wave = threadIdx.x >> 6, lane = threadIdx.x & 63;
  const int r16 = lane & 15, quad = lane >> 4;

  if (blockIdx.x < 512) {
    const int m0 = blockIdx.x * 64 + wave * 16;
    u16x8 av[4];
    const float* arow = x + (size_t)(m0 + r16) * DIM + quad * 8;
    #pragma unroll
    for (int kk = 0; kk < 4; ++kk) {
      float4 a0 = *(const float4*)(arow + kk * 32);
      float4 a1 = *(const float4*)(arow + kk * 32 + 4);
      u16x8 au;
      au[0] = f2bf(a0.x); au[1] = f2bf(a0.y); au[2] = f2bf(a0.z); au[3] = f2bf(a0.w);
      au[4] = f2bf(a1.x); au[5] = f2bf(a1.y); au[6] = f2bf(a1.z); au[7] = f2bf(a1.w);
      av[kk] = au;
    }
    #pragma unroll
    for (int g = 0; g < 6; ++g) {
      f32x4 acc[4];
      const f32x4 z = {0.f, 0.f, 0.f, 0.f};
      acc[0] = z; acc[1] = z; acc[2] = z; acc[3] = z;
      #pragma unroll
      for (int kk = 0; kk < 4; ++kk) {
        #pragma unroll
        for (int s = 0; s < 4; ++s) {
          u16x8 bu = *(const u16x8*)(CW + (size_t)(g * 64 + s * 16 + r16) * DIM + kk * 32 + quad * 8);
          acc[s] = __builtin_amdgcn_mfma_f32_16x16x32_bf16(
              __builtin_bit_cast(bf16x8, bu), __builtin_bit_cast(bf16x8, av[kk]), acc[s], 0, 0, 0);
        }
      }
      const int arr = g >> 1;               // 0:q 1:K 2:V
      const int colbase = (g & 1) * 64;
      unsigned short* dst = arr == 0 ? qb : (arr == 1 ? Kb : Vb);
      const int m = m0 + r16;
      #pragma unroll
      for (int s = 0; s < 4; ++s) {
        const int j0 = colbase + s * 16 + quad * 4;
        float4 b4 = {0.f, 0.f, 0.f, 0.f};
        if (arr == 0) {
          float4 t = *(const float4*)(bq + j0);
          b4.x = 0.25f * t.x; b4.y = 0.25f * t.y; b4.z = 0.25f * t.z; b4.w = 0.25f * t.w;
        } else if (arr == 2) {
          b4 = *(const float4*)(bv + j0);
        }
        u32 lo = (u32)f2bf(acc[s][0] + b4.x) | ((u32)f2bf(acc[s][1] + b4.y) << 16);
        u32 hi = (u32)f2bf(acc[s][2] + b4.z) | ((u32)f2bf(acc[s][3] + b4.w) << 16);
        uint2 st = {lo, hi};
        *(uint2*)(dst + (size_t)m * DIM + j0) = st;
      }
    }
  } else {
    const int idx = blockIdx.x - 512;
    const int m0 = (idx >> 1) * 64 + wave * 16;
    const int n0 = (idx & 1) * 64;
    f32x4 acc[4];
    const f32x4 z = {0.f, 0.f, 0.f, 0.f};
    acc[0] = z; acc[1] = z; acc[2] = z; acc[3] = z;
    const float* arow = ea + (size_t)(m0 + r16) * EDIM + quad * 8;
    #pragma unroll
    for (int kk = 0; kk < 2; ++kk) {
      float4 a0 = *(const float4*)(arow + kk * 32);
      float4 a1 = *(const float4*)(arow + kk * 32 + 4);
      u16x8 au;
      au[0] = f2bf(a0.x); au[1] = f2bf(a0.y); au[2] = f2bf(a0.z); au[3] = f2bf(a0.w);
      au[4] = f2bf(a1.x); au[5] = f2bf(a1.y); au[6] = f2bf(a1.z); au[7] = f2bf(a1.w);
      bf16x8 av = __builtin_bit_cast(bf16x8, au);
      #pragma unroll
      for (int s = 0; s < 4; ++s) {
        u16x8 bu = *(const u16x8*)(CWE + (size_t)(n0 + s * 16 + r16) * EDIM + kk * 32 + quad * 8);
        acc[s] = __builtin_amdgcn_mfma_f32_16x16x32_bf16(
            __builtin_bit_cast(bf16x8, bu), av, acc[s], 0, 0, 0);
      }
    }
    const int m = m0 + r16;
    #pragma unroll
    for (int s = 0; s < 4; ++s) {
      const int j0 = n0 + s * 16 + quad * 4;
      float4 b4 = *(const float4*)(bk + j0);
      u32 lo = (u32)f2bf(acc[s][0] + b4.x) | ((u32)f2bf(acc[s][1] + b4.y) << 16);
      u32 hi = (u32)f2bf(acc[s][2] + b4.z) | ((u32)f2bf(acc[s][3] + b4.w) << 16);
      uint2 st = {lo, hi};
      *(uint2*)(WeKb + (size_t)m * DIM + j0) = st;
    }
  }
}

// ---------------- G3: per-node attention (1 block = 1 wave = 1 node) ----------
// r2 structure (best measured: 66.3 us). uidx[n][32] + nedges[n] loaded in
// parallel (one round trip). Issue order pinned by memory-clobber asm:
//   idx (9, oldest) -> q nt-loads (8) -> [fence] -> K/E DMA (36) -> [fence]
//   -> V loads (32, youngest) -> asm s_waitcnt vmcnt(32)
// vmcnt(32) retires exactly idx+q+DMA (9+8+36=53), leaving the 32 V loads in
// flight under score/softmax. This kernel is at the random-256B-gather BW
// floor (dur = FETCH/3.3 TB/s, occupancy-insensitive: 17% vs 74% -> same dur).
__global__ __launch_bounds__(64, 4) void attn_kernel(
    const unsigned short* __restrict__ qb, const unsigned short* __restrict__ Kb,
    const unsigned short* __restrict__ Vb, const unsigned short* __restrict__ WeKb,
    const int* __restrict__ nedges, const int* __restrict__ uidx,
    unsigned short* __restrict__ ctxb)
{
  __shared__ __align__(16) unsigned char ldsK[32 * 272];  // K rows, stride 272
  __shared__ __align__(16) unsigned char ldsE[4 * 272];   // WeK rows
  __shared__ __align__(16) float ldsP[8][36];             // P, padded stride
  const int lane = threadIdx.x;
  const int n = blockIdx.x;
  const int l = lane & 31, half = lane >> 5;
  const int h = lane >> 3;                                 // ctx head
  const int c0 = lane * 2;                                 // ctx dim pair

  // --- indices: flattened neighbor rows + edge ids, all independent (1 RT) ---
  const i32x4* up = (const i32x4*)(uidx + (size_t)n * 32);
  i32x4 m0 = __builtin_nontemporal_load(up + 0);
  i32x4 m1 = __builtin_nontemporal_load(up + 1);
  i32x4 m2 = __builtin_nontemporal_load(up + 2);
  i32x4 m3 = __builtin_nontemporal_load(up + 3);
  i32x4 m4 = __builtin_nontemporal_load(up + 4);
  i32x4 m5 = __builtin_nontemporal_load(up + 5);
  i32x4 m6 = __builtin_nontemporal_load(up + 6);
  i32x4 m7 = __builtin_nontemporal_load(up + 7);
  i32x4 e4 = __builtin_nontemporal_load((const i32x4*)(nedges + (size_t)n * DEG));

  // --- q (wave-uniform row): nontemporal, issued before the index wait ---
  const u32x4* qp = (const u32x4*)(qb + (size_t)n * DIM + half * 64);
  u32x4 qv[8];
  #pragma unroll
  for (int ch = 0; ch < 8; ++ch) qv[ch] = __builtin_nontemporal_load(qp + ch);

  // Fence 0: pins idx+q issue before the DMAs (keeps vmcnt math exact).
  asm volatile("" ::: "memory");

  // --- K + WeK rows -> LDS DMA (36 instrs) ---
#define STAGE(ldsdst, table, row) do {                                          \
    const u32* gp_ = (const u32*)((table) + (size_t)(row) * DIM) + lane;        \
    __builtin_amdgcn_global_load_lds(                                           \
        (const __attribute__((address_space(1))) u32*)gp_,                      \
        (__attribute__((address_space(3))) u32*)(ldsdst), 4, 0, 0);             \
  } while (0)
  STAGE(ldsK + 0  * 272, Kb, m0.x); STAGE(ldsK + 1  * 272, Kb, m0.y);
  STAGE(ldsK + 2  * 272, Kb, m0.z); STAGE(ldsK + 3  * 272, Kb, m0.w);
  STAGE(ldsK + 4  * 272, Kb, m1.x); STAGE(ldsK + 5  * 272, Kb, m1.y);
  STAGE(ldsK + 6  * 272, Kb, m1.z); STAGE(ldsK + 7  * 272, Kb, m1.w);
  STAGE(ldsK + 8  * 272, Kb, m2.x); STAGE(ldsK + 9  * 272, Kb, m2.y);
  STAGE(ldsK + 10 * 272, Kb, m2.z); STAGE(ldsK + 11 * 272, Kb, m2.w);
  STAGE(ldsK + 12 * 272, Kb, m3.x); STAGE(ldsK + 13 * 272, Kb, m3.y);
  STAGE(ldsK + 14 * 272, Kb, m3.z); STAGE(ldsK + 15 * 272, Kb, m3.w);
  STAGE(ldsK + 16 * 272, Kb, m4.x); STAGE(ldsK + 17 * 272, Kb, m4.y);
  STAGE(ldsK + 18 * 272, Kb, m4.z); STAGE(ldsK + 19 * 272, Kb, m4.w);
  STAGE(ldsK + 20 * 272, Kb, m5.x); STAGE(ldsK + 21 * 272, Kb, m5.y);
  STAGE(ldsK + 22 * 272, Kb, m5.z); STAGE(ldsK + 23 * 272, Kb, m5.w);
  STAGE(ldsK + 24 * 272, Kb, m6.x); STAGE(ldsK + 25 * 272, Kb, m6.y);
  STAGE(ldsK + 26 * 272, Kb, m6.z); STAGE(ldsK + 27 * 272, Kb, m6.w);
  STAGE(ldsK + 28 * 272, Kb, m7.x); STAGE(ldsK + 29 * 272, Kb, m7.y);
  STAGE(ldsK + 30 * 272, Kb, m7.z); STAGE(ldsK + 31 * 272, Kb, m7.w);
  STAGE(ldsE + 0 * 272, WeKb, e4.x); STAGE(ldsE + 1 * 272, WeKb, e4.y);
  STAGE(ldsE + 2 * 272, WeKb, e4.z); STAGE(ldsE + 3 * 272, WeKb, e4.w);
#undef STAGE

  // Fence 1: pins DMA issue before V issue (makes vmcnt(32) math exact).
  asm volatile("" ::: "memory");

  // --- V rows (coalesced 256 B wave reads) -> regs: youngest 32 VMEM ops ---
  u32 vv[32];
#define VLOAD(t, row) vv[t] = *(const u32*)(Vb + (size_t)(row) * DIM + c0)
  VLOAD(0,  m0.x); VLOAD(1,  m0.y); VLOAD(2,  m0.z); VLOAD(3,  m0.w);
  VLOAD(4,  m1.x); VLOAD(5,  m1.y); VLOAD(6,  m1.z); VLOAD(7,  m1.w);
  VLOAD(8,  m2.x); VLOAD(9,  m2.y); VLOAD(10, m2.z); VLOAD(11, m2.w);
  VLOAD(12, m3.x); VLOAD(13, m3.y); VLOAD(14, m3.z); VLOAD(15, m3.w);
  VLOAD(16, m4.x); VLOAD(17, m4.y); VLOAD(18, m4.z); VLOAD(19, m4.w);
  VLOAD(20, m5.x); VLOAD(21, m5.y); VLOAD(22, m5.z); VLOAD(23, m5.w);
  VLOAD(24, m6.x); VLOAD(25, m6.y); VLOAD(26, m6.z); VLOAD(27, m6.w);
  VLOAD(28, m7.x); VLOAD(29, m7.y); VLOAD(30, m7.z); VLOAD(31, m7.w);
#undef VLOAD

  // Fence 2: retire exactly the oldest 53 ops (idx + q + all DMAs); the 32 V
  // loads remain in flight under the score/softmax compute below.
  asm volatile("s_waitcnt vmcnt(32)" ::: "memory");

  // --- scores: s[hi] = q . (K[l] + WeK[e(l)]) over this half's 64 dims ---
  const unsigned char* krow = ldsK + l * 272 + half * 128;
  const unsigned char* erow = ldsE + (l >> 3) * 272 + half * 128;
  float s[4] = {0.f, 0.f, 0.f, 0.f};
  #pragma unroll
  for (int ch = 0; ch < 8; ++ch) {
    uint4 kc = *(const uint4*)(krow + ch * 16);
    uint4 ec = *(const uint4*)(erow + ch * 16);
    const int hi = ch >> 1;
    float t = s[hi];
    t = dot2bf(qv[ch].x, kc.x, t); t = dot2bf(qv[ch].x, ec.x, t);
    t = dot2bf(qv[ch].y, kc.y, t); t = dot2bf(qv[ch].y, ec.y, t);
    t = dot2bf(qv[ch].z, kc.z, t); t = dot2bf(qv[ch].z, ec.z, t);
    t = dot2bf(qv[ch].w, kc.w, t); t = dot2bf(qv[ch].w, ec.w, t);
    s[hi] = t;
  }

  // --- softmax over the 32 keys (within each 32-lane half-group) ---
  #pragma unroll
  for (int hi = 0; hi < 4; ++hi) {
    float vmax = s[hi];
    #pragma unroll
    for (int off = 16; off >= 1; off >>= 1)
      vmax = fmaxf(vmax, __shfl_xor(vmax, off, 32));
    float ex = __expf(s[hi] - vmax);
    float sum = ex;
    #pragma unroll
    for (int off = 16; off >= 1; off >>= 1)
      sum += __shfl_xor(sum, off, 32);
    ldsP[half * 4 + hi][l] = ex / sum;
  }
  // single-wave block: LDS write->read ordering is just lgkmcnt (compiler).

  // --- ctx: lane = dim pair; V regs (compiler waits precisely), P via LDS ---
  float a0 = 0.f, a1 = 0.f;
  #pragma unroll
  for (int t = 0; t < 8; ++t) {
    float4 p4 = *(const float4*)&ldsP[h][t * 4];
    a0 = fmaf(p4.x, bflo(vv[t * 4 + 0]), a0); a1 = fmaf(p4.x, bfhi(vv[t * 4 + 0]), a1);
    a0 = fmaf(p4.y, bflo(vv[t * 4 + 1]), a0); a1 = fmaf(p4.y, bfhi(vv[t * 4 + 1]), a1);
    a0 = fmaf(p4.z, bflo(vv[t * 4 + 2]), a0); a1 = fmaf(p4.z, bfhi(vv[t * 4 + 2]), a1);
    a0 = fmaf(p4.w, bflo(vv[t * 4 + 3]), a0); a1 = fmaf(p4.w, bfhi(vv[t * 4 + 3]), a1);
  }
  unsigned int pk = (unsigned int)f2bf(a0) | ((unsigned int)f2bf(a1) << 16);
  __builtin_nontemporal_store(pk, (u32*)(ctxb + (size_t)n * DIM + c0));
}

// ---------------- G4: ctx[N,128] @ Wo[128,128]^T + bo, ReLU -> out fp32 -------
// Operand-swapped MFMA -> lane owns 4 consecutive out columns = float4 store.
// One block per 64 rows computes both column halves (Wob reuse).
__global__ __launch_bounds__(256) void g4_kernel(
    const unsigned short* __restrict__ ctxb, const unsigned short* __restrict__ Wob,
    const float* __restrict__ bo, float* __restrict__ out)
{
  const int wave = threadIdx.x >> 6, lane = threadIdx.x & 63;
  const int r16 = lane & 15, quad = lane >> 4;
  const int m0 = blockIdx.x * 64 + wave * 16;

  f32x4 acc[2][4];
  const f32x4 z = {0.f, 0.f, 0.f, 0.f};
  #pragma unroll
  for (int hf = 0; hf < 2; ++hf) { acc[hf][0] = z; acc[hf][1] = z; acc[hf][2] = z; acc[hf][3] = z; }

  #pragma unroll
  for (int kk = 0; kk < 4; ++kk) {
    u16x8 au = *(const u16x8*)(ctxb + (size_t)(m0 + r16) * DIM + kk * 32 + quad * 8);
    bf16x8 av = __builtin_bit_cast(bf16x8, au);
    #pragma unroll
    for (int hf = 0; hf < 2; ++hf) {
      #pragma unroll
      for (int s = 0; s < 4; ++s) {
        u16x8 bu = *(const u16x8*)(Wob + (size_t)(hf * 64 + s * 16 + r16) * DIM + kk * 32 + quad * 8);
        acc[hf][s] = __builtin_amdgcn_mfma_f32_16x16x32_bf16(
            __builtin_bit_cast(bf16x8, bu), av, acc[hf][s], 0, 0, 0);
      }
    }
  }

  const int m = m0 + r16;
  #pragma unroll
  for (int hf = 0; hf < 2; ++hf) {
    #pragma unroll
    for (int s = 0; s < 4; ++s) {
      const int j0 = hf * 64 + s * 16 + quad * 4;
      float4 b4 = *(const float4*)(bo + j0);
      float4 v;
      v.x = acc[hf][s][0] + b4.x; v.x = v.x > 0.f ? v.x : 0.f;
      v.y = acc[hf][s][1] + b4.y; v.y = v.y > 0.f ? v.y : 0.f;
      v.z = acc[hf][s][2] + b4.z; v.z = v.z > 0.f ? v.z : 0.f;
      v.w = acc[hf][s][3] + b4.w; v.w = v.w > 0.f ? v.w : 0.f;
      *(float4*)(out + (size_t)m * DIM + j0) = v;
    }
  }
}

extern "C" void kernel_launch(void* const* d_in, const int* in_sizes, int n_in,
                              void* d_out, int out_size, void* d_ws, size_t ws_size,
                              hipStream_t stream)
{
  const float* x     = (const float*)d_in[0];
  const float* ea    = (const float*)d_in[1];
  const int* nedges  = (const int*)d_in[2];
  const int* enodes  = (const int*)d_in[3];
  const float* Wlin  = (const float*)d_in[4];
  const float* Wedge = (const float*)d_in[5];
  const float* Wq    = (const float*)d_in[6];
  const float* Wk    = (const float*)d_in[7];
  const float* Wv    = (const float*)d_in[8];
  const float* bq    = (const float*)d_in[9];
  const float* bk    = (const float*)d_in[10];
  const float* bv    = (const float*)d_in[11];
  const float* Wo    = (const float*)d_in[12];
  const float* bo    = (const float*)d_in[13];
  float* out = (float*)d_out;

  unsigned short* wsp = (unsigned short*)d_ws;
  unsigned short* CW   = wsp;  wsp += 384 * 128;
  unsigned short* CWE  = wsp;  wsp += 128 * 64;
  unsigned short* Wob  = wsp;  wsp += 128 * 128;
  unsigned short* qb   = wsp;  wsp += (size_t)N_NODES * DIM;
  unsigned short* Kb   = wsp;  wsp += (size_t)N_NODES * DIM;
  unsigned short* Vb   = wsp;  wsp += (size_t)N_NODES * DIM;
  unsigned short* WeKb = wsp;  wsp += (size_t)N_EDGES * DIM;
  unsigned short* ctxb = wsp;  wsp += (size_t)N_NODES * DIM;
  int* uidx = (int*)wsp;       wsp += (size_t)N_NODES * 32 * 2;  // 32 ints/node

  // 288 blocks of weight-prep + 512 blocks of uidx flattening
  wprep_kernel<<<dim3(800), dim3(256), 0, stream>>>(
      Wq, Wk, Wv, Wlin, Wedge, Wo, nedges, enodes, CW, CWE, Wob, uidx);
  g12_kernel<<<dim3(1024), dim3(256), 0, stream>>>(x, CW, bq, bv, qb, Kb, Vb, ea, CWE, bk, WeKb);
  attn_kernel<<<dim3(32768), dim3(64), 0, stream>>>(qb, Kb, Vb, WeKb, nedges, uidx, ctxb);
  g4_kernel<<<dim3(512), dim3(256), 0, stream>>>(ctxb, Wob, bo, out);
}